// Round 5
// baseline (384.039 us; speedup 1.0000x reference)
//
#include <hip/hip_runtime.h>

#define SS 2048
#define BB 32
#define DD 1024
#define RB 16   // batch rows per block
#define GT 8    // t-steps per block

typedef unsigned short u16;
typedef unsigned int u32;
using f32x4 = __attribute__((ext_vector_type(4))) float;
using bf16x8 = __attribute__((ext_vector_type(8))) short;

__device__ __forceinline__ u16 f2bf(float x) {
  union { float f; u32 u; } c; c.f = x;
  u32 r = c.u + 0x7fffu + ((c.u >> 16) & 1u);
  return (u16)(r >> 16);
}
__device__ __forceinline__ float bf2f(u32 h) {
  union { u32 u; float f; } c; c.u = h << 16; return c.f;
}
// XOR swizzle for row-stride-2048B bf16 tiles (verified R1-R4): spreads
// cross-row same-col ds_read_b128 A-frag loads across banks; 16B chunks intact.
__device__ __forceinline__ int swzb(int row, int col) {
  return ((row << 11) + (col << 1)) ^ ((row & 7) << 4);
}
__device__ __forceinline__ void st8(u16* base, int row, int col, float4 a, float4 b) {
  uint4 pk;
  pk.x = (u32)f2bf(a.x) | ((u32)f2bf(a.y) << 16);
  pk.y = (u32)f2bf(a.z) | ((u32)f2bf(a.w) << 16);
  pk.z = (u32)f2bf(b.x) | ((u32)f2bf(b.y) << 16);
  pk.w = (u32)f2bf(b.z) | ((u32)f2bf(b.w) << 16);
  *reinterpret_cast<uint4*>(reinterpret_cast<char*>(base) + swzb(row, col)) = pk;
}
__device__ __forceinline__ void st8z(u16* base, int row, int col) {
  uint4 pk; pk.x = pk.y = pk.z = pk.w = 0u;
  *reinterpret_cast<uint4*>(reinterpret_cast<char*>(base) + swzb(row, col)) = pk;
}
__device__ __forceinline__ uint4 ld16(const u16* base, int row, int col) {
  return *reinterpret_cast<const uint4*>(reinterpret_cast<const char*>(base) + swzb(row, col));
}
__device__ __forceinline__ bf16x8 ld_afrag(const u16* base, int row, int col) {
  return *reinterpret_cast<const bf16x8*>(reinterpret_cast<const char*>(base) + swzb(row, col));
}
// tanh-form GELU, branch-free (v_exp_f32). |err| vs exact < ~3e-4.
__device__ __forceinline__ float gelu_f(float v) {
  const float u2 = 1.5957691216057308f * v * __builtin_fmaf(0.044715f, v * v, 1.0f);
  const float e = __expf(u2);
  const float th = 1.0f - 2.0f * __builtin_amdgcn_rcpf(e + 1.0f);
  return 0.5f * v * (1.0f + th);
}
// full-row LN stats: 16 elems/lane over a 64-lane wave (fp32 inputs).
__device__ __forceinline__ void rowstats(float4 a, float4 b, float4 c, float4 d,
                                         float& mu, float& rs) {
  float s1 = a.x + a.y + a.z + a.w + b.x + b.y + b.z + b.w +
             c.x + c.y + c.z + c.w + d.x + d.y + d.z + d.w;
  float s2 = a.x*a.x + a.y*a.y + a.z*a.z + a.w*a.w + b.x*b.x + b.y*b.y + b.z*b.z + b.w*b.w +
             c.x*c.x + c.y*c.y + c.z*c.z + c.w*c.w + d.x*d.x + d.y*d.y + d.z*d.z + d.w*d.w;
#pragma unroll
  for (int off = 32; off; off >>= 1) { s1 += __shfl_xor(s1, off); s2 += __shfl_xor(s2, off); }
  mu = s1 * (1.f / 1024.f);
  rs = rsqrtf(s2 * (1.f / 1024.f) - mu * mu + 1e-5f);
}

// W [H][128][64] f32 -> bf16 MFMA B-frags; gamma folded into the top (c) half.
__global__ void prep_w2(const float* __restrict__ W, const float* __restrict__ gamma,
                        u16* __restrict__ Wf) {
  const int o = blockIdx.x * 256 + threadIdx.x;
  const int l = o & 63;
  const int tile = o >> 6;
  const int nt = tile & 3, ks = (tile >> 2) & 3, h = tile >> 4;
  const int d = nt * 16 + (l & 15);
  const int kbw = ks * 32 + 8 * (l >> 4);
  u16 v[8];
#pragma unroll
  for (int j = 0; j < 8; ++j) {
    const int k = kbw + j;
    float w = W[(h * 128 + k) * 64 + d];
    if (ks < 2) w *= gamma[h * 64 + k];   // top half multiplies LN'd values
    v[j] = f2bf(w);
  }
  uint4 pk;
  pk.x = (u32)v[0] | ((u32)v[1] << 16);
  pk.y = (u32)v[2] | ((u32)v[3] << 16);
  pk.z = (u32)v[4] | ((u32)v[5] << 16);
  pk.w = (u32)v[6] | ((u32)v[7] << 16);
  reinterpret_cast<uint4*>(Wf)[o] = pk;
}

// vg[d] = sum_k gamma[h*64+k]*W_top[k,d] ; bias2[d] = bias[d] + sum_k beta[..]*W_top[k,d]
__global__ void prep_v(const float* __restrict__ W, const float* __restrict__ gamma,
                       const float* __restrict__ beta, const float* __restrict__ bias,
                       float* __restrict__ vg, float* __restrict__ bias2) {
  const int d = blockIdx.x * 256 + threadIdx.x;
  const int h = d >> 6, dd = d & 63;
  float sg = 0.f, sb = 0.f;
  for (int k = 0; k < 64; ++k) {
    const float w = W[(h * 128 + k) * 64 + dd];
    sg += gamma[h * 64 + k] * w;
    sb += beta[h * 64 + k] * w;
  }
  vg[d] = sg;
  bias2[d] = bias[d] + sb;
}

__global__ __launch_bounds__(512, 4) void lienet_main(
    const float* __restrict__ src, const u16* __restrict__ Wf,
    const float* __restrict__ vg, const float* __restrict__ bias2,
    const float* __restrict__ bias, const float* __restrict__ gamma,
    const float* __restrict__ beta, float* __restrict__ out) {
  __shared__ __align__(16) u16 bufA[RB * DD];   // 32 KB: s_r * x(t-1), bf16
  __shared__ __align__(16) u16 bufB[RB * DD];   // 32 KB: x(t), bf16
  __shared__ float2 part[RB][8];                // final-LN partials
  __shared__ float pm[RB];                      // mu_r * s_r of x(t-1)

  const int bid = blockIdx.x;                   // 512 blocks = 256 t-chunks x 2 row-groups
  const int t0 = (bid >> 1) * GT;
  const int rg = bid & 1;
  const int tid = threadIdx.x;
  const int wave = tid >> 6;                    // 0..7
  const int lane = tid & 63;
  const int cl = lane & 15;
  const int rq = lane >> 4;
  const int kb = rq * 8;
  const int c0 = lane * 8;
  const int r0 = wave * 2;                      // this wave stages rows r0, r0+1
  const uint4* wfu = reinterpret_cast<const uint4*>(Wf);

  // ---- prologue: stage x(t0) into bufB, s*x(t0-1) into bufA ----
  float cur_mu[2], cur_s[2];   // stats of the 2 rows this wave owns in bufB
#pragma unroll
  for (int rr = 0; rr < 2; ++rr) {
    const int row = r0 + rr;
    const int grow = rg * RB + row;
    const float* xp = src + ((size_t)t0 * BB + grow) * DD;
    float4 a0 = *reinterpret_cast<const float4*>(xp + c0);
    float4 a1 = *reinterpret_cast<const float4*>(xp + c0 + 4);
    float4 a2 = *reinterpret_cast<const float4*>(xp + 512 + c0);
    float4 a3 = *reinterpret_cast<const float4*>(xp + 512 + c0 + 4);
    rowstats(a0, a1, a2, a3, cur_mu[rr], cur_s[rr]);
    st8(bufB, row, c0, a0, a1);
    st8(bufB, row, 512 + c0, a2, a3);
    if (t0 == 0) {
      st8z(bufA, row, c0);
      st8z(bufA, row, 512 + c0);
      if (lane == 0) pm[row] = 0.f;
    } else {
      const float* cp = src + ((size_t)(t0 - 1) * BB + grow) * DD;
      float4 b0 = *reinterpret_cast<const float4*>(cp + c0);
      float4 b1 = *reinterpret_cast<const float4*>(cp + c0 + 4);
      float4 b2 = *reinterpret_cast<const float4*>(cp + 512 + c0);
      float4 b3 = *reinterpret_cast<const float4*>(cp + 512 + c0 + 4);
      float pmu, ps;
      rowstats(b0, b1, b2, b3, pmu, ps);
      b0.x *= ps; b0.y *= ps; b0.z *= ps; b0.w *= ps;
      b1.x *= ps; b1.y *= ps; b1.z *= ps; b1.w *= ps;
      b2.x *= ps; b2.y *= ps; b2.z *= ps; b2.w *= ps;
      b3.x *= ps; b3.y *= ps; b3.z *= ps; b3.w *= ps;
      st8(bufA, row, c0, b0, b1);
      st8(bufA, row, 512 + c0, b2, b3);
      if (lane == 0) pm[row] = pmu * ps;
    }
  }
  __syncthreads();

  // ---- main loop ----
  for (int t = t0; t < t0 + GT; ++t) {
    const bool stage = (t + 1 < t0 + GT);

    // phase 1: MFMA — A from LDS, B streamed from L2-resident Wf
    f32x4 acc[2][4];
#pragma unroll
    for (int hh = 0; hh < 2; ++hh)
#pragma unroll
      for (int nt = 0; nt < 4; ++nt) acc[hh][nt] = (f32x4){0.f, 0.f, 0.f, 0.f};
#pragma unroll
    for (int ks = 0; ks < 4; ++ks) {
      const u16* sb = (ks < 2) ? bufA : bufB;   // cat = [c ; x]
#pragma unroll
      for (int hh = 0; hh < 2; ++hh) {
        const int h = wave * 2 + hh;
        bf16x8 afr = ld_afrag(sb, cl, h * 64 + (ks & 1) * 32 + kb);
        const uint4* wp = wfu + ((h * 4 + ks) * 4) * 64 + lane;
#pragma unroll
        for (int nt = 0; nt < 4; ++nt) {
          uint4 wv = wp[nt * 64];
          acc[hh][nt] = __builtin_amdgcn_mfma_f32_16x16x32_bf16(
              afr, *reinterpret_cast<bf16x8*>(&wv), acc[hh][nt], 0, 0, 0);
        }
      }
    }

    // phase 2: issue x(t+1) prefetch (consumed in phase 4; ~full latency hidden)
    float4 nx[2][4];
    if (stage) {
#pragma unroll
      for (int rr = 0; rr < 2; ++rr) {
        const float* xp = src + ((size_t)(t + 1) * BB + rg * RB + r0 + rr) * DD;
        nx[rr][0] = *reinterpret_cast<const float4*>(xp + c0);
        nx[rr][1] = *reinterpret_cast<const float4*>(xp + c0 + 4);
        nx[rr][2] = *reinterpret_cast<const float4*>(xp + 512 + c0);
        nx[rr][3] = *reinterpret_cast<const float4*>(xp + 512 + c0 + 4);
      }
    }

    // phase 3: bias + mu-correction + GELU; per-row LN partials
    const float* bptr = (t == 0) ? bias : bias2;
    float pmv[4];
#pragma unroll
    for (int j = 0; j < 4; ++j) pmv[j] = pm[rq * 4 + j];
#pragma unroll
    for (int hh = 0; hh < 2; ++hh)
#pragma unroll
      for (int nt = 0; nt < 4; ++nt) {
        const int d = (wave * 2 + hh) * 64 + nt * 16 + cl;
        const float bt = bptr[d];
        const float vgv = vg[d];
#pragma unroll
        for (int j = 0; j < 4; ++j) {
          const float v = acc[hh][nt][j] + bt - pmv[j] * vgv;
          acc[hh][nt][j] = gelu_f(v);
        }
      }
#pragma unroll
    for (int j = 0; j < 4; ++j) {
      float a = 0.f, b = 0.f;
#pragma unroll
      for (int hh = 0; hh < 2; ++hh)
#pragma unroll
        for (int nt = 0; nt < 4; ++nt) {
          const float g = acc[hh][nt][j];
          a += g; b += g * g;
        }
      a += __shfl_xor(a, 1); b += __shfl_xor(b, 1);
      a += __shfl_xor(a, 2); b += __shfl_xor(b, 2);
      a += __shfl_xor(a, 4); b += __shfl_xor(b, 4);
      a += __shfl_xor(a, 8); b += __shfl_xor(b, 8);
      if (cl == 0) part[rq * 4 + j][wave] = make_float2(a, b);
    }
    __syncthreads();   // bar1: MFMA A-reads done; partials visible

    // phase 4a: merge LN stats, write out(t)
#pragma unroll
    for (int j = 0; j < 4; ++j) {
      const int row = rq * 4 + j;
      float2 pe = part[row][cl & 7];
      float a = pe.x, b = pe.y;
      a += __shfl_xor(a, 1); b += __shfl_xor(b, 1);
      a += __shfl_xor(a, 2); b += __shfl_xor(b, 2);
      a += __shfl_xor(a, 4); b += __shfl_xor(b, 4);
      const float mu = a * (1.f / 1024.f);
      const float rs = rsqrtf(b * (1.f / 1024.f) - mu * mu + 1e-5f);
      float* op = out + ((size_t)t * BB + rg * RB + row) * DD;
#pragma unroll
      for (int hh = 0; hh < 2; ++hh)
#pragma unroll
        for (int nt = 0; nt < 4; ++nt) {
          const int d = (wave * 2 + hh) * 64 + nt * 16 + cl;
          op[d] = (acc[hh][nt][j] - mu) * rs * gamma[d] + beta[d];
        }
    }

    // phase 4b: bufA <- s*x(t) (from bf16 bufB readback), bufB <- x(t+1)
    if (stage) {
#pragma unroll
      for (int rr = 0; rr < 2; ++rr) {
        const int row = r0 + rr;
        const float sc = cur_s[rr];
        uint4 g0 = ld16(bufB, row, c0);
        uint4 g1 = ld16(bufB, row, 512 + c0);
        float4 a0, a1, a2, a3;
        a0.x = bf2f(g0.x & 0xffffu) * sc; a0.y = bf2f(g0.x >> 16) * sc;
        a0.z = bf2f(g0.y & 0xffffu) * sc; a0.w = bf2f(g0.y >> 16) * sc;
        a1.x = bf2f(g0.z & 0xffffu) * sc; a1.y = bf2f(g0.z >> 16) * sc;
        a1.z = bf2f(g0.w & 0xffffu) * sc; a1.w = bf2f(g0.w >> 16) * sc;
        a2.x = bf2f(g1.x & 0xffffu) * sc; a2.y = bf2f(g1.x >> 16) * sc;
        a2.z = bf2f(g1.y & 0xffffu) * sc; a2.w = bf2f(g1.y >> 16) * sc;
        a3.x = bf2f(g1.z & 0xffffu) * sc; a3.y = bf2f(g1.z >> 16) * sc;
        a3.z = bf2f(g1.w & 0xffffu) * sc; a3.w = bf2f(g1.w >> 16) * sc;
        st8(bufA, row, c0, a0, a1);
        st8(bufA, row, 512 + c0, a2, a3);
        if (lane == 0) pm[row] = cur_mu[rr] * cur_s[rr];
        rowstats(nx[rr][0], nx[rr][1], nx[rr][2], nx[rr][3], cur_mu[rr], cur_s[rr]);
        st8(bufB, row, c0, nx[rr][0], nx[rr][1]);
        st8(bufB, row, 512 + c0, nx[rr][2], nx[rr][3]);
      }
    }
    __syncthreads();   // bar2: new tiles/pm staged
  }
}

extern "C" void kernel_launch(void* const* d_in, const int* in_sizes, int n_in,
                              void* d_out, int out_size, void* d_ws, size_t ws_size,
                              hipStream_t stream) {
  const float* src = (const float*)d_in[0];
  const float* W = (const float*)d_in[1];
  const float* bias = (const float*)d_in[2];
  const float* gamma = (const float*)d_in[3];
  const float* beta = (const float*)d_in[4];
  float* out = (float*)d_out;
  u16* Wf = (u16*)d_ws;                               // 256 KB
  float* vgp = (float*)((char*)d_ws + 262144);        // 4 KB
  float* b2p = vgp + 1024;                            // 4 KB

  prep_w2<<<64, 256, 0, stream>>>(W, gamma, Wf);
  prep_v<<<4, 256, 0, stream>>>(W, gamma, beta, bias, vgp, b2p);
  lienet_main<<<(SS / GT) * 2, 512, 0, stream>>>(src, Wf, vgp, b2p, bias, gamma, beta, out);
}

// Round 6
// 221.852 us; speedup vs baseline: 1.7311x; 1.7311x over previous
//
#include <hip/hip_runtime.h>

#define SS 2048
#define BB 32
#define DD 1024
#define RB 8    // batch rows per block (M=16 MFMA with rows 8-15 duplicated)

typedef unsigned short u16;
typedef unsigned int u32;
using f32x4 = __attribute__((ext_vector_type(4))) float;
using bf16x8 = __attribute__((ext_vector_type(8))) short;

__device__ __forceinline__ u16 f2bf(float x) {
  union { float f; u32 u; } c; c.f = x;
  u32 r = c.u + 0x7fffu + ((c.u >> 16) & 1u);
  return (u16)(r >> 16);
}
// XOR swizzle for row-stride-2048B bf16 tiles (verified R1-R5): spreads
// cross-row same-col ds_read_b128 A-frag loads across 8 16B slots.
__device__ __forceinline__ int swzb(int row, int col) {
  return ((row << 11) + (col << 1)) ^ ((row & 7) << 4);
}
__device__ __forceinline__ void st8(u16* base, int row, int col, float4 a, float4 b) {
  uint4 pk;
  pk.x = (u32)f2bf(a.x) | ((u32)f2bf(a.y) << 16);
  pk.y = (u32)f2bf(a.z) | ((u32)f2bf(a.w) << 16);
  pk.z = (u32)f2bf(b.x) | ((u32)f2bf(b.y) << 16);
  pk.w = (u32)f2bf(b.z) | ((u32)f2bf(b.w) << 16);
  *reinterpret_cast<uint4*>(reinterpret_cast<char*>(base) + swzb(row, col)) = pk;
}
__device__ __forceinline__ void st8z(u16* base, int row, int col) {
  uint4 pk; pk.x = pk.y = pk.z = pk.w = 0u;
  *reinterpret_cast<uint4*>(reinterpret_cast<char*>(base) + swzb(row, col)) = pk;
}
__device__ __forceinline__ bf16x8 ld_afrag(const u16* base, int row, int col) {
  return *reinterpret_cast<const bf16x8*>(reinterpret_cast<const char*>(base) + swzb(row, col));
}
// tanh-form GELU, branch-free (v_exp_f32). |err| vs exact < ~3e-4.
__device__ __forceinline__ float gelu_f(float v) {
  const float u2 = 1.5957691216057308f * v * __builtin_fmaf(0.044715f, v * v, 1.0f);
  const float e = __expf(u2);
  const float th = 1.0f - 2.0f * __builtin_amdgcn_rcpf(e + 1.0f);
  return 0.5f * v * (1.0f + th);
}
// full-row LN stats: 16 elems/lane over a 64-lane wave (fp32 inputs).
__device__ __forceinline__ void rowstats(float4 a, float4 b, float4 c, float4 d,
                                         float& mu, float& rs) {
  float s1 = a.x + a.y + a.z + a.w + b.x + b.y + b.z + b.w +
             c.x + c.y + c.z + c.w + d.x + d.y + d.z + d.w;
  float s2 = a.x*a.x + a.y*a.y + a.z*a.z + a.w*a.w + b.x*b.x + b.y*b.y + b.z*b.z + b.w*b.w +
             c.x*c.x + c.y*c.y + c.z*c.z + c.w*c.w + d.x*d.x + d.y*d.y + d.z*d.z + d.w*d.w;
#pragma unroll
  for (int off = 32; off; off >>= 1) { s1 += __shfl_xor(s1, off); s2 += __shfl_xor(s2, off); }
  mu = s1 * (1.f / 1024.f);
  rs = rsqrtf(s2 * (1.f / 1024.f) - mu * mu + 1e-5f);
}

// W [H][128][64] f32 -> bf16 MFMA B-frags; gamma folded into the top (c) half.
__global__ void prep_w2(const float* __restrict__ W, const float* __restrict__ gamma,
                        u16* __restrict__ Wf) {
  const int o = blockIdx.x * 256 + threadIdx.x;
  const int l = o & 63;
  const int tile = o >> 6;
  const int nt = tile & 3, ks = (tile >> 2) & 3, h = tile >> 4;
  const int d = nt * 16 + (l & 15);
  const int kbw = ks * 32 + 8 * (l >> 4);
  u16 v[8];
#pragma unroll
  for (int j = 0; j < 8; ++j) {
    const int k = kbw + j;
    float w = W[(h * 128 + k) * 64 + d];
    if (ks < 2) w *= gamma[h * 64 + k];   // top half multiplies LN'd values
    v[j] = f2bf(w);
  }
  uint4 pk;
  pk.x = (u32)v[0] | ((u32)v[1] << 16);
  pk.y = (u32)v[2] | ((u32)v[3] << 16);
  pk.z = (u32)v[4] | ((u32)v[5] << 16);
  pk.w = (u32)v[6] | ((u32)v[7] << 16);
  reinterpret_cast<uint4*>(Wf)[o] = pk;
}

// vg[d] = sum_k gamma[h*64+k]*W_top[k,d] ; bias2[d] = bias[d] + sum_k beta[..]*W_top[k,d]
__global__ void prep_v(const float* __restrict__ W, const float* __restrict__ gamma,
                       const float* __restrict__ beta, const float* __restrict__ bias,
                       float* __restrict__ vg, float* __restrict__ bias2) {
  const int d = blockIdx.x * 256 + threadIdx.x;
  const int h = d >> 6, dd = d & 63;
  float sg = 0.f, sb = 0.f;
  for (int k = 0; k < 64; ++k) {
    const float w = W[(h * 128 + k) * 64 + dd];
    sg += gamma[h * 64 + k] * w;
    sb += beta[h * 64 + k] * w;
  }
  vg[d] = sg;
  bias2[d] = bias[d] + sb;
}

__global__ __launch_bounds__(256, 4) void lienet_main(
    const float* __restrict__ src, const u16* __restrict__ Wf,
    const float* __restrict__ vg, const float* __restrict__ bias2,
    const float* __restrict__ bias, const float* __restrict__ gamma,
    const float* __restrict__ beta, float* __restrict__ out) {
  __shared__ __align__(16) u16 cbuf[RB * DD];   // 16 KB: s_r * x(t-1), bf16
  __shared__ __align__(16) u16 xbuf[RB * DD];   // 16 KB: x(t), bf16
  __shared__ float part[4][RB][2];              // per-wave LN partials
  __shared__ float pm[RB];                      // mu_r * s_r of x(t-1)

  // bid -> (t, row-group): XCD x owns t in [x*256,(x+1)*256) -> block(t+1)'s
  // c-read of src[t] hits the same XCD's L2 that block(t) just fetched into.
  const int bid = blockIdx.x;
  const int lin = (bid & 7) * 1024 + (bid >> 3);
  const int t = lin >> 2;
  const int rg = lin & 3;

  const int tid = threadIdx.x;
  const int wave = tid >> 6;
  const int lane = tid & 63;
  const int c0 = lane * 16;
  const uint4* wfu = reinterpret_cast<const uint4*>(Wf);

  // ---------------- staging: wave w owns rows 2w, 2w+1 ----------------
#pragma unroll
  for (int rr = 0; rr < 2; ++rr) {
    const int row = wave * 2 + rr;
    const int grow = rg * RB + row;
    // issue ALL loads first (x(t) + x(t-1)), then process
    const float* xp = src + ((size_t)t * BB + grow) * DD + c0;
    float4 x0 = *reinterpret_cast<const float4*>(xp);
    float4 x1 = *reinterpret_cast<const float4*>(xp + 4);
    float4 x2 = *reinterpret_cast<const float4*>(xp + 8);
    float4 x3 = *reinterpret_cast<const float4*>(xp + 12);
    if (t > 0) {
      const float* cp = src + ((size_t)(t - 1) * BB + grow) * DD + c0;
      float4 y0 = *reinterpret_cast<const float4*>(cp);
      float4 y1 = *reinterpret_cast<const float4*>(cp + 4);
      float4 y2 = *reinterpret_cast<const float4*>(cp + 8);
      float4 y3 = *reinterpret_cast<const float4*>(cp + 12);
      st8(xbuf, row, c0, x0, x1);
      st8(xbuf, row, c0 + 8, x2, x3);
      float pmu, ps;
      rowstats(y0, y1, y2, y3, pmu, ps);
      y0.x *= ps; y0.y *= ps; y0.z *= ps; y0.w *= ps;
      y1.x *= ps; y1.y *= ps; y1.z *= ps; y1.w *= ps;
      y2.x *= ps; y2.y *= ps; y2.z *= ps; y2.w *= ps;
      y3.x *= ps; y3.y *= ps; y3.z *= ps; y3.w *= ps;
      st8(cbuf, row, c0, y0, y1);
      st8(cbuf, row, c0 + 8, y2, y3);
      if (lane == 0) pm[row] = pmu * ps;
    } else {
      st8(xbuf, row, c0, x0, x1);
      st8(xbuf, row, c0 + 8, x2, x3);
      st8z(cbuf, row, c0);
      st8z(cbuf, row, c0 + 8);
      if (lane == 0) pm[row] = 0.f;
    }
  }
  __syncthreads();

  // ---------------- matmul: wave w -> heads 4w..4w+3, M=16 (rows 8-15 dup) ----------------
  f32x4 acc[4][4];
#pragma unroll
  for (int hh = 0; hh < 4; ++hh)
#pragma unroll
    for (int nt = 0; nt < 4; ++nt) acc[hh][nt] = (f32x4){0.f, 0.f, 0.f, 0.f};

  const int arow = lane & 7;          // rows 8-15 of the MFMA M-dim duplicate 0-7
  const int kb = 8 * (lane >> 4);
#pragma unroll
  for (int ks = 0; ks < 4; ++ks) {
    const u16* sb = (ks < 2) ? cbuf : xbuf;   // cat = [s*x_prev ; x]
#pragma unroll
    for (int hh = 0; hh < 4; ++hh) {
      const int h = wave * 4 + hh;
      bf16x8 a = ld_afrag(sb, arow, h * 64 + (ks & 1) * 32 + kb);
      const uint4* wp = wfu + ((h * 4 + ks) * 4) * 64 + lane;
#pragma unroll
      for (int nt = 0; nt < 4; ++nt) {
        uint4 wv = wp[nt * 64];
        acc[hh][nt] = __builtin_amdgcn_mfma_f32_16x16x32_bf16(
            a, *reinterpret_cast<bf16x8*>(&wv), acc[hh][nt], 0, 0, 0);
      }
    }
  }

  // ---------------- epilogue: bias2 + mu-correction + GELU ----------------
  // lanes<32 own heads {4w,4w+1}, lanes>=32 own {4w+2,4w+3} (dup'd C rows).
  const int hilo = lane >> 5;
  const int row4 = 4 * ((lane >> 4) & 1);
  const int cl = lane & 15;
  const float* bptr = (t == 0) ? bias : bias2;
  float pmv[4];
#pragma unroll
  for (int r = 0; r < 4; ++r) pmv[r] = pm[row4 + r];
  float gv[2][4][4];
#pragma unroll
  for (int hp = 0; hp < 2; ++hp) {
    const int h_eff = wave * 4 + hp + 2 * hilo;
#pragma unroll
    for (int nt = 0; nt < 4; ++nt) {
      const int d = h_eff * 64 + nt * 16 + cl;
      const float bt = bptr[d];
      const float vgv = vg[d];
#pragma unroll
      for (int r = 0; r < 4; ++r) {
        const float v = (hilo ? acc[hp + 2][nt][r] : acc[hp][nt][r]) + bt - pmv[r] * vgv;
        gv[hp][nt][r] = gelu_f(v);
      }
    }
  }
  // per-row LN partials: xor 1,2,4,8 within 16-lane group, xor 32 merges head-halves
  float s1[4], s2[4];
#pragma unroll
  for (int r = 0; r < 4; ++r) {
    float a = 0.f, b = 0.f;
#pragma unroll
    for (int hp = 0; hp < 2; ++hp)
#pragma unroll
      for (int nt = 0; nt < 4; ++nt) {
        const float g = gv[hp][nt][r];
        a += g; b += g * g;
      }
    a += __shfl_xor(a, 1); b += __shfl_xor(b, 1);
    a += __shfl_xor(a, 2); b += __shfl_xor(b, 2);
    a += __shfl_xor(a, 4); b += __shfl_xor(b, 4);
    a += __shfl_xor(a, 8); b += __shfl_xor(b, 8);
    a += __shfl_xor(a, 32); b += __shfl_xor(b, 32);
    s1[r] = a; s2[r] = b;
  }
  if (lane == 0 || lane == 16) {
#pragma unroll
    for (int r = 0; r < 4; ++r) {
      part[wave][row4 + r][0] = s1[r];
      part[wave][row4 + r][1] = s2[r];
    }
  }
  // preload epilogue gamma/beta under the barrier
  float gm[2][4], bt2[2][4];
#pragma unroll
  for (int hp = 0; hp < 2; ++hp) {
    const int h_eff = wave * 4 + hp + 2 * hilo;
#pragma unroll
    for (int nt = 0; nt < 4; ++nt) {
      const int d = h_eff * 64 + nt * 16 + cl;
      gm[hp][nt] = gamma[d];
      bt2[hp][nt] = beta[d];
    }
  }
  __syncthreads();

  // ---------------- merge LN stats, write out ----------------
#pragma unroll
  for (int r = 0; r < 4; ++r) {
    const int row = row4 + r;
    const float a = part[0][row][0] + part[1][row][0] + part[2][row][0] + part[3][row][0];
    const float b = part[0][row][1] + part[1][row][1] + part[2][row][1] + part[3][row][1];
    const float mu = a * (1.f / 1024.f);
    const float rs = rsqrtf(b * (1.f / 1024.f) - mu * mu + 1e-5f);
    float* op = out + ((size_t)t * BB + rg * RB + row) * DD;
#pragma unroll
    for (int hp = 0; hp < 2; ++hp) {
      const int h_eff = wave * 4 + hp + 2 * hilo;
#pragma unroll
      for (int nt = 0; nt < 4; ++nt)
        op[h_eff * 64 + nt * 16 + cl] = (gv[hp][nt][r] - mu) * rs * gm[hp][nt] + bt2[hp][nt];
    }
  }
}

extern "C" void kernel_launch(void* const* d_in, const int* in_sizes, int n_in,
                              void* d_out, int out_size, void* d_ws, size_t ws_size,
                              hipStream_t stream) {
  const float* src = (const float*)d_in[0];
  const float* W = (const float*)d_in[1];
  const float* bias = (const float*)d_in[2];
  const float* gamma = (const float*)d_in[3];
  const float* beta = (const float*)d_in[4];
  float* out = (float*)d_out;
  u16* Wf = (u16*)d_ws;                               // 256 KB
  float* vgp = (float*)((char*)d_ws + 262144);        // 4 KB
  float* b2p = vgp + 1024;                            // 4 KB

  prep_w2<<<64, 256, 0, stream>>>(W, gamma, Wf);
  prep_v<<<4, 256, 0, stream>>>(W, gamma, beta, bias, vgp, b2p);
  lienet_main<<<SS * 4, 256, 0, stream>>>(src, Wf, vgp, b2p, bias, gamma, beta, out);
}